// Round 5
// baseline (21.074 us; speedup 1.0000x reference)
//
#include <hip/hip_runtime.h>
#include <math.h>

#define T_LEN 1600
#define D_DIM 64
#define WIN   50
#define NPT   48            // N = WINDOW - (TAK_DIM-1)*TAK_TAU
#define NPAIR 1128          // N*(N-1)/2 unique pairs
#define VPL   18            // ceil(1128/64) values per lane for median wave
#define K_MED 563           // lower-median rank among 1128 unique pair dists

// H1 features (beta1_med, ent1, maxp1, land1) are identically zero:
// beta1(r) = edges - N + comps is the graph cycle rank, monotone
// non-decreasing along the sorted-radii filtration, so `ends` never fires.
// Only H0 (Prim MST deaths) + the pair-distance median matter.
//
// DPP wave reduction (rocPRIM-style masked sequence), proven in R4.
template <typename F>
__device__ __forceinline__ int dpp_red63(int v, F op) {
    int t;
    t = __builtin_amdgcn_update_dpp(v, v, 0xb1, 0xf, 0xf, false); v = op(v, t); // quad [1,0,3,2]
    t = __builtin_amdgcn_update_dpp(v, v, 0x4e, 0xf, 0xf, false); v = op(v, t); // quad [2,3,0,1]
    t = __builtin_amdgcn_update_dpp(v, v, 0x114, 0xf, 0xe, false); v = op(v, t); // row_shr:4
    t = __builtin_amdgcn_update_dpp(v, v, 0x118, 0xf, 0xc, false); v = op(v, t); // row_shr:8
    t = __builtin_amdgcn_update_dpp(v, v, 0x142, 0xa, 0xf, false); v = op(v, t); // row_bcast:15
    t = __builtin_amdgcn_update_dpp(v, v, 0x143, 0xc, 0xf, false); v = op(v, t); // row_bcast:31
    return v;
}
__device__ __forceinline__ float wave_fmin_bc(float v) {
    int r = dpp_red63(__float_as_int(v), [](int a, int b) {
        return __float_as_int(fminf(__int_as_float(a), __int_as_float(b))); });
    return __int_as_float(__builtin_amdgcn_readlane(r, 63));
}
__device__ __forceinline__ float wave_fmax_bc(float v) {
    int r = dpp_red63(__float_as_int(v), [](int a, int b) {
        return __float_as_int(fmaxf(__int_as_float(a), __int_as_float(b))); });
    return __int_as_float(__builtin_amdgcn_readlane(r, 63));
}
__device__ __forceinline__ float wave_fadd_bc(float v) {
    int r = dpp_red63(__float_as_int(v), [](int a, int b) {
        return __float_as_int(__fadd_rn(__int_as_float(a), __int_as_float(b))); });
    return __int_as_float(__builtin_amdgcn_readlane(r, 63));
}
__device__ __forceinline__ unsigned wave_umin_bc(unsigned v) {
    int r = dpp_red63((int)v, [](int a, int b) {
        unsigned ua = (unsigned)a, ub = (unsigned)b;
        return (int)(ua < ub ? ua : ub); });
    return (unsigned)__builtin_amdgcn_readlane(r, 63);
}

#define CDV(k) case k: dv = colD[k]; break;

__global__ __launch_bounds__(128)
void topo_feats_kernel(const float* __restrict__ latent,
                       const float* __restrict__ W,
                       const float* __restrict__ bvec,
                       float* __restrict__ out)
{
    __shared__ float s_series[WIN];
    __shared__ float s_sq[NPT];
    __shared__ float s_D[NPT * NPT];
    __shared__ float s_med;

    const int w    = blockIdx.x;         // window id
    const int bb   = w >> 5;             // batch
    const int kk   = w & 31;             // window within batch
    const int tid  = threadIdx.x;
    const int wv   = tid >> 6;
    const int lane = tid & 63;

    // ---- P0. prefetch linear-head weights; HBM latency hides under Prim
    float pb = 0.0f, pw0 = 0.0f, pw2 = 0.0f, pw4 = 0.0f, pw6 = 0.0f;
    if (wv == 0 && lane < 8) {
        pb  = bvec[lane];
        pw0 = W[lane * 8 + 0];
        pw2 = W[lane * 8 + 2];
        pw4 = W[lane * 8 + 4];
        pw6 = W[lane * 8 + 6];
    }

    // ---- P1a. wave 0: series norms (vectorized loads; accumulation order
    //           bit-identical to passing versions: r[q] += p[8k+q]^2)
    if (wv == 0) {
        float x0 = 0.0f;
        if (lane < WIN) {
            const float4* p4 = (const float4*)(latent +
                ((size_t)bb * T_LEN + (size_t)kk * WIN + lane) * D_DIM);
            float r[8];
#pragma unroll
            for (int q = 0; q < 8; ++q) r[q] = 0.0f;
#pragma unroll
            for (int i = 0; i < 16; i += 2) {
                float4 a = p4[i], b = p4[i + 1];
                r[0] = __fadd_rn(r[0], __fmul_rn(a.x, a.x));
                r[1] = __fadd_rn(r[1], __fmul_rn(a.y, a.y));
                r[2] = __fadd_rn(r[2], __fmul_rn(a.z, a.z));
                r[3] = __fadd_rn(r[3], __fmul_rn(a.w, a.w));
                r[4] = __fadd_rn(r[4], __fmul_rn(b.x, b.x));
                r[5] = __fadd_rn(r[5], __fmul_rn(b.y, b.y));
                r[6] = __fadd_rn(r[6], __fmul_rn(b.z, b.z));
                r[7] = __fadd_rn(r[7], __fmul_rn(b.w, b.w));
            }
            float ss = __fadd_rn(__fadd_rn(__fadd_rn(r[0], r[1]), __fadd_rn(r[2], r[3])),
                                 __fadd_rn(__fadd_rn(r[4], r[5]), __fadd_rn(r[6], r[7])));
            x0 = sqrtf(ss);
        }
        float x1 = __shfl_down(x0, 1);
        float x2 = __shfl_down(x0, 2);
        if (lane < WIN) s_series[lane] = x0;
        if (lane < NPT)
            s_sq[lane] = __fadd_rn(__fadd_rn(__fmul_rn(x0, x0), __fmul_rn(x1, x1)),
                                   __fmul_rn(x2, x2));
    }
    __syncthreads();

    // ---- P1b. pairwise distances, both waves (arithmetic identical)
#pragma unroll
    for (int k = 0; k < NPT * NPT / 128; ++k) {
        int e = tid + 128 * k;
        int i = e / NPT, j = e - i * NPT;
        float dot = fmaf(s_series[i + 2], s_series[j + 2],
                    fmaf(s_series[i + 1], s_series[j + 1],
                         __fmul_rn(s_series[i], s_series[j])));
        float d2 = __fsub_rn(__fadd_rn(s_sq[i], s_sq[j]), __fmul_rn(2.0f, dot));
        s_D[i * NPT + j] = sqrtf(fmaxf(d2, 0.0f));
    }
    __syncthreads();

    float dreg = 0.0f;                   // lane `it` holds MST death `it`

    if (wv == 0) {
        // ---- P2a. Prim MST; D column in registers (D symmetric:
        //           colD[j] = D[j][lane]); per-iter fetch of D[id][lane]
        //           is a register select on wave-uniform id (jump table).
        float colD[NPT];
        const int src = (lane < NPT) ? lane : NPT - 1;
#pragma unroll
        for (int j = 0; j < NPT; ++j) colD[j] = s_D[j * NPT + src];

        bool  intree = (lane == 0);
        float mind   = colD[0];          // D[0][lane]
#pragma unroll 1
        for (int it = 0; it < NPT - 1; ++it) {
            float cand = (intree || lane >= NPT) ? 1e30f : mind;
            float wmin = wave_fmin_bc(cand);
            if (lane == it) dreg = wmin;
            // lowest-index argmin (== jnp.argmin; multiset tie-invariant)
            unsigned long long m = __ballot(cand == wmin);
            int id = __ffsll(m) - 1;
            if (lane == id) intree = true;
            float dv;
            switch (id) {
                CDV(0)  CDV(1)  CDV(2)  CDV(3)  CDV(4)  CDV(5)  CDV(6)  CDV(7)
                CDV(8)  CDV(9)  CDV(10) CDV(11) CDV(12) CDV(13) CDV(14) CDV(15)
                CDV(16) CDV(17) CDV(18) CDV(19) CDV(20) CDV(21) CDV(22) CDV(23)
                CDV(24) CDV(25) CDV(26) CDV(27) CDV(28) CDV(29) CDV(30) CDV(31)
                CDV(32) CDV(33) CDV(34) CDV(35) CDV(36) CDV(37) CDV(38) CDV(39)
                CDV(40) CDV(41) CDV(42) CDV(43) CDV(44) CDV(45) CDV(46) CDV(47)
                default: dv = 1e30f; break;
            }
            mind = fminf(mind, dv);
        }
    } else {
        // ---- P2b. exact median of 1128 unique pair distances (bitwise
        //           binary search; ballot+popc counts). Triangular decode
        //           closed-form: 9025-8*off(i) = (95-2i)^2 exactly.
        unsigned ub[VPL];
#pragma unroll
        for (int r = 0; r < VPL; ++r) {
            int e = lane + 64 * r;
            unsigned v = 0xFFFFFFFFu;                 // sentinel: never < probe
            if (e < NPAIR) {
                int i = (int)((95.0f - sqrtf((float)(9025 - 8 * e))) * 0.5f);
                i = (i < 0) ? 0 : ((i > NPT - 2) ? NPT - 2 : i);
                int offi = (i * (95 - i)) >> 1;
                int offn = ((i + 1) * (94 - i)) >> 1;
                if (e >= offn)      { ++i; offi = offn; }
                else if (e < offi)  { --i; offi = (i * (95 - i)) >> 1; }
                int j = i + 1 + (e - offi);
                v = __float_as_uint(s_D[i * NPT + j]);
            }
            ub[r] = v;
        }
        unsigned lo = 0;
        for (int bit = 30; bit >= 0; --bit) {
            unsigned probe = lo | (1u << bit);
            int c = 0;
#pragma unroll
            for (int r = 0; r < VPL; ++r)
                c += __popcll(__ballot(ub[r] < probe));
            if (c <= K_MED) lo = probe;
        }
        const unsigned v0 = lo;                        // rank-563 value
        int cle = 0; unsigned mn = 0xFFFFFFFFu;
#pragma unroll
        for (int r = 0; r < VPL; ++r) {
            cle += __popcll(__ballot(ub[r] <= v0));
            if (ub[r] > v0 && ub[r] < mn) mn = ub[r];
        }
        mn = wave_umin_bc(mn);
        unsigned v1 = (cle >= K_MED + 2) ? v0 : mn;    // rank-564 value
        if (lane == 0)
            s_med = __fadd_rn(__fmul_rn(0.5f, __uint_as_float(v0)),
                              __fmul_rn(0.5f, __uint_as_float(v1)));
    }
    __syncthreads();

    // ---- P3. wave-parallel H0 features + linear head (wave 0)
    if (wv == 0) {
        const float rmed = s_med;
        const bool  isd  = (lane < NPT - 1);
        const float d    = isd ? dreg : 0.0f;

        float beta0 = (float)__popcll(__ballot(isd && (d > rmed)));
        float mx    = wave_fmax_bc(isd ? d : -INFINITY);

        float sv = (isd && d > 0.0f) ? d : 0.0f;
        float ss = wave_fadd_bc(sv);

        float p    = sv / ss;                          // ss > 0 always here
        float term = (p > 0.0f) ? -p * logf(p) : 0.0f;
        float ent  = wave_fadd_bc(term);

        // landscape: births=0 => lam(t) = clamp(min(t, mx - t)), t in [0,mx]
        float step = mx / 19.0f;
        float t    = step * (float)lane;
        float lam  = (lane < 20) ? fmaxf(fminf(t, mx - t), 0.0f) : 0.0f;
        float land = wave_fadd_bc(lam) * (1.0f / 20.0f);

        // feats = [beta0, 0, ent0, 0, maxp0, 0, land0, 0] @ W.T + b
        if (lane < 8) {
            float o = pb + beta0 * pw0 + ent * pw2 + mx * pw4 + land * pw6;
            out[w * 8 + lane] = o;
        }
    }
}

extern "C" void kernel_launch(void* const* d_in, const int* in_sizes, int n_in,
                              void* d_out, int out_size, void* d_ws, size_t ws_size,
                              hipStream_t stream)
{
    const float* latent = (const float*)d_in[0];
    const float* W      = (const float*)d_in[1];
    const float* bvec   = (const float*)d_in[2];
    float*       out    = (float*)d_out;

    topo_feats_kernel<<<dim3(256), dim3(128), 0, stream>>>(latent, W, bvec, out);

    (void)in_sizes; (void)n_in; (void)out_size; (void)d_ws; (void)ws_size;
}

// Round 6
// 18.961 us; speedup vs baseline: 1.1114x; 1.1114x over previous
//
#include <hip/hip_runtime.h>
#include <math.h>

#define T_LEN 1600
#define D_DIM 64
#define WIN   50
#define NPT   48            // N = WINDOW - (TAK_DIM-1)*TAK_TAU
#define NPAIR 1128          // N*(N-1)/2 unique pairs
#define VPL   18            // ceil(1128/64) values per lane for median wave
#define K_MED 563           // lower-median rank among 1128 unique pair dists

// H1 features (beta1_med, ent1, maxp1, land1) are identically zero:
// beta1(r) = edges - N + comps is the graph cycle rank, monotone
// non-decreasing along the sorted-radii filtration, so `ends` never fires.
// Only H0 (Prim MST deaths) + the pair-distance median matter.
//
// DPP wave reduction (rocPRIM-style masked sequence), proven in R4.
template <typename F>
__device__ __forceinline__ int dpp_red63(int v, F op) {
    int t;
    t = __builtin_amdgcn_update_dpp(v, v, 0xb1, 0xf, 0xf, false); v = op(v, t); // quad [1,0,3,2]
    t = __builtin_amdgcn_update_dpp(v, v, 0x4e, 0xf, 0xf, false); v = op(v, t); // quad [2,3,0,1]
    t = __builtin_amdgcn_update_dpp(v, v, 0x114, 0xf, 0xe, false); v = op(v, t); // row_shr:4
    t = __builtin_amdgcn_update_dpp(v, v, 0x118, 0xf, 0xc, false); v = op(v, t); // row_shr:8
    t = __builtin_amdgcn_update_dpp(v, v, 0x142, 0xa, 0xf, false); v = op(v, t); // row_bcast:15
    t = __builtin_amdgcn_update_dpp(v, v, 0x143, 0xc, 0xf, false); v = op(v, t); // row_bcast:31
    return v;
}
__device__ __forceinline__ float wave_fmin_bc(float v) {
    int r = dpp_red63(__float_as_int(v), [](int a, int b) {
        return __float_as_int(fminf(__int_as_float(a), __int_as_float(b))); });
    return __int_as_float(__builtin_amdgcn_readlane(r, 63));
}
__device__ __forceinline__ float wave_fmax_bc(float v) {
    int r = dpp_red63(__float_as_int(v), [](int a, int b) {
        return __float_as_int(fmaxf(__int_as_float(a), __int_as_float(b))); });
    return __int_as_float(__builtin_amdgcn_readlane(r, 63));
}
__device__ __forceinline__ float wave_fadd_bc(float v) {
    int r = dpp_red63(__float_as_int(v), [](int a, int b) {
        return __float_as_int(__fadd_rn(__int_as_float(a), __int_as_float(b))); });
    return __int_as_float(__builtin_amdgcn_readlane(r, 63));
}
__device__ __forceinline__ unsigned wave_umin_bc(unsigned v) {
    int r = dpp_red63((int)v, [](int a, int b) {
        unsigned ua = (unsigned)a, ub = (unsigned)b;
        return (int)(ua < ub ? ua : ub); });
    return (unsigned)__builtin_amdgcn_readlane(r, 63);
}

__global__ __launch_bounds__(256)
void topo_feats_kernel(const float* __restrict__ latent,
                       const float* __restrict__ W,
                       const float* __restrict__ bvec,
                       float* __restrict__ out)
{
    __shared__ float s_series[WIN];
    __shared__ float s_sq[NPT];
    __shared__ float s_D[NPT * NPT];
    __shared__ float s_med;

    const int w    = blockIdx.x;         // window id
    const int bb   = w >> 5;             // batch
    const int kk   = w & 31;             // window within batch
    const int tid  = threadIdx.x;
    const int wv   = tid >> 6;
    const int lane = tid & 63;

    // ---- P0. prefetch linear-head weights: in R4 these HBM loads were
    //          after the last barrier (~900cy exposed); issued here they
    //          complete for free under P1/P2.
    float pb = 0.0f, pw0 = 0.0f, pw2 = 0.0f, pw4 = 0.0f, pw6 = 0.0f;
    if (wv == 0 && lane < 8) {
        pb  = bvec[lane];
        pw0 = W[lane * 8 + 0];
        pw2 = W[lane * 8 + 2];
        pw4 = W[lane * 8 + 4];
        pw6 = W[lane * 8 + 6];
    }

    // ---- P1a. wave 0: series norms; float4 loads (R5-proven numerics:
    //           accumulation order identical to scalar r[q] += p[8k+q]^2)
    if (wv == 0) {
        float x0 = 0.0f;
        if (lane < WIN) {
            const float4* p4 = (const float4*)(latent +
                ((size_t)bb * T_LEN + (size_t)kk * WIN + lane) * D_DIM);
            float r[8];
#pragma unroll
            for (int q = 0; q < 8; ++q) r[q] = 0.0f;
#pragma unroll
            for (int i = 0; i < 16; i += 2) {
                float4 a = p4[i], b = p4[i + 1];
                r[0] = __fadd_rn(r[0], __fmul_rn(a.x, a.x));
                r[1] = __fadd_rn(r[1], __fmul_rn(a.y, a.y));
                r[2] = __fadd_rn(r[2], __fmul_rn(a.z, a.z));
                r[3] = __fadd_rn(r[3], __fmul_rn(a.w, a.w));
                r[4] = __fadd_rn(r[4], __fmul_rn(b.x, b.x));
                r[5] = __fadd_rn(r[5], __fmul_rn(b.y, b.y));
                r[6] = __fadd_rn(r[6], __fmul_rn(b.z, b.z));
                r[7] = __fadd_rn(r[7], __fmul_rn(b.w, b.w));
            }
            float ss = __fadd_rn(__fadd_rn(__fadd_rn(r[0], r[1]), __fadd_rn(r[2], r[3])),
                                 __fadd_rn(__fadd_rn(r[4], r[5]), __fadd_rn(r[6], r[7])));
            x0 = sqrtf(ss);
        }
        float x1 = __shfl_down(x0, 1);
        float x2 = __shfl_down(x0, 2);
        if (lane < WIN) s_series[lane] = x0;
        if (lane < NPT)
            s_sq[lane] = __fadd_rn(__fadd_rn(__fmul_rn(x0, x0), __fmul_rn(x1, x1)),
                                   __fmul_rn(x2, x2));
    }
    __syncthreads();

    // ---- P1b. pairwise distances, all 4 waves (arithmetic identical)
    for (int e = tid; e < NPT * NPT; e += 256) {
        int i = e / NPT, j = e - i * NPT;
        float dot = fmaf(s_series[i + 2], s_series[j + 2],
                    fmaf(s_series[i + 1], s_series[j + 1],
                         __fmul_rn(s_series[i], s_series[j])));
        float d2 = __fsub_rn(__fadd_rn(s_sq[i], s_sq[j]), __fmul_rn(2.0f, dot));
        s_D[i * NPT + j] = sqrtf(fmaxf(d2, 0.0f));
    }
    __syncthreads();

    float dreg = 0.0f;                   // lane `it` holds MST death `it`

    if (wv == 0) {
        // ---- P2a. Prim MST deaths; DPP argmin + LDS row read (R4-proven)
        bool  intree = (lane == 0);
        float mind   = (lane < NPT) ? s_D[lane] : 1e30f;   // row 0
        for (int it = 0; it < NPT - 1; ++it) {
            float cand = (intree || lane >= NPT) ? 1e30f : mind;
            float wmin = wave_fmin_bc(cand);               // uniform (SGPR)
            if (lane == it) dreg = wmin;
            // lowest-index argmin (== jnp.argmin; multiset tie-invariant)
            unsigned long long m = __ballot(cand == wmin);
            int id = __ffsll(m) - 1;
            if (lane == id) intree = true;
            if (lane < NPT) mind = fminf(mind, s_D[id * NPT + lane]);
        }
    } else if (wv == 1) {
        // ---- P2b. exact median of 1128 unique pair distances via bitwise
        //           binary search; counts via ballot+popc. Triangular decode
        //           closed-form: 9025-8*off(i) = (95-2i)^2 exactly.
        unsigned ub[VPL];
#pragma unroll
        for (int r = 0; r < VPL; ++r) {
            int e = lane + 64 * r;
            unsigned v = 0xFFFFFFFFu;                 // sentinel: never < probe
            if (e < NPAIR) {
                int i = (int)((95.0f - sqrtf((float)(9025 - 8 * e))) * 0.5f);
                i = (i < 0) ? 0 : ((i > NPT - 2) ? NPT - 2 : i);
                int offi = (i * (95 - i)) >> 1;
                int offn = ((i + 1) * (94 - i)) >> 1;
                if (e >= offn)      { ++i; offi = offn; }
                else if (e < offi)  { --i; offi = (i * (95 - i)) >> 1; }
                int j = i + 1 + (e - offi);
                v = __float_as_uint(s_D[i * NPT + j]);
            }
            ub[r] = v;
        }
        unsigned lo = 0;
        for (int bit = 30; bit >= 0; --bit) {
            unsigned probe = lo | (1u << bit);
            int c = 0;
#pragma unroll
            for (int r = 0; r < VPL; ++r)
                c += __popcll(__ballot(ub[r] < probe));
            if (c <= K_MED) lo = probe;
        }
        const unsigned v0 = lo;                        // rank-563 value
        int cle = 0; unsigned mn = 0xFFFFFFFFu;
#pragma unroll
        for (int r = 0; r < VPL; ++r) {
            cle += __popcll(__ballot(ub[r] <= v0));
            if (ub[r] > v0 && ub[r] < mn) mn = ub[r];
        }
        mn = wave_umin_bc(mn);
        unsigned v1 = (cle >= K_MED + 2) ? v0 : mn;    // rank-564 value
        if (lane == 0)
            s_med = __fadd_rn(__fmul_rn(0.5f, __uint_as_float(v0)),
                              __fmul_rn(0.5f, __uint_as_float(v1)));
    }
    __syncthreads();

    // ---- P3. wave-parallel H0 features + linear head (wave 0)
    if (wv == 0) {
        const float rmed = s_med;
        const bool  isd  = (lane < NPT - 1);
        const float d    = isd ? dreg : 0.0f;

        float beta0 = (float)__popcll(__ballot(isd && (d > rmed)));
        float mx    = wave_fmax_bc(isd ? d : -INFINITY);

        float sv = (isd && d > 0.0f) ? d : 0.0f;
        float ss = wave_fadd_bc(sv);

        float p    = sv / ss;                          // ss > 0 always here
        float term = (p > 0.0f) ? -p * logf(p) : 0.0f;
        float ent  = wave_fadd_bc(term);

        // landscape: births=0 => lam(t) = clamp(min(t, mx - t)), t in [0,mx]
        float step = mx / 19.0f;
        float t    = step * (float)lane;
        float lam  = (lane < 20) ? fmaxf(fminf(t, mx - t), 0.0f) : 0.0f;
        float land = wave_fadd_bc(lam) * (1.0f / 20.0f);

        // feats = [beta0, 0, ent0, 0, maxp0, 0, land0, 0] @ W.T + b
        if (lane < 8) {
            float o = pb + beta0 * pw0 + ent * pw2 + mx * pw4 + land * pw6;
            out[w * 8 + lane] = o;
        }
    }
}

extern "C" void kernel_launch(void* const* d_in, const int* in_sizes, int n_in,
                              void* d_out, int out_size, void* d_ws, size_t ws_size,
                              hipStream_t stream)
{
    const float* latent = (const float*)d_in[0];
    const float* W      = (const float*)d_in[1];
    const float* bvec   = (const float*)d_in[2];
    float*       out    = (float*)d_out;

    topo_feats_kernel<<<dim3(256), dim3(256), 0, stream>>>(latent, W, bvec, out);

    (void)in_sizes; (void)n_in; (void)out_size; (void)d_ws; (void)ws_size;
}